// Round 2
// baseline (7025.997 us; speedup 1.0000x reference)
//
#include <hip/hip_runtime.h>

// ---------------------------------------------------------------------------
// Transformer encoder, 6 layers, B=4 S=1024 D=1024 H=16 Dk=64 F=4096.
// Round 1: GEMMs on bf16 MFMA with hi/lo split (3-pass) for fp32-level
// accuracy. Attention + LayerNorm remain fp32 vector.
// ---------------------------------------------------------------------------

#define D_MODEL 1024
#define N_HEAD 16
#define D_K 64
#define D_FF 4096
#define SEQ 1024
#define BATCH 4
#define ROWS (BATCH * SEQ)   // 4096
#define LAYERS 6

typedef __attribute__((ext_vector_type(4))) float floatx4;
typedef __attribute__((ext_vector_type(8))) short shortx8;
typedef __attribute__((ext_vector_type(8))) unsigned short ushortx8;
typedef __attribute__((ext_vector_type(4))) unsigned short ushortx4;

__device__ __forceinline__ unsigned short f32_to_bf16(float f) {
  unsigned int u = __float_as_uint(f);
  u = u + 0x7FFFu + ((u >> 16) & 1u);   // RNE
  return (unsigned short)(u >> 16);
}
__device__ __forceinline__ float bf16_to_f32(unsigned short s) {
  return __uint_as_float(((unsigned int)s) << 16);
}

// ---------------------------- weight transpose + split ----------------------
// src fp32 [K,N] row-major -> dst_hi/dst_lo bf16 bits [N,K] row-major.
__global__ __launch_bounds__(256) void wtrans_kernel(
    const float* __restrict__ W, unsigned short* __restrict__ th,
    unsigned short* __restrict__ tl, int K, int N) {
  __shared__ float tile[32][33];
  const int tid = threadIdx.x;
  const int k0 = blockIdx.x * 32;
  const int n0 = blockIdx.y * 32;
  {
    const int r = tid >> 3;
    const int c4 = (tid & 7) * 4;
    float4 v = *(const float4*)&W[(size_t)(k0 + r) * N + n0 + c4];
    tile[r][c4 + 0] = v.x; tile[r][c4 + 1] = v.y;
    tile[r][c4 + 2] = v.z; tile[r][c4 + 3] = v.w;
  }
  __syncthreads();
  {
    const int n = tid >> 3;
    const int k4 = (tid & 7) * 4;
    ushortx4 h, l;
#pragma unroll
    for (int j = 0; j < 4; ++j) {
      float f = tile[k4 + j][n];
      unsigned short hb = f32_to_bf16(f);
      h[j] = hb;
      l[j] = f32_to_bf16(f - bf16_to_f32(hb));
    }
    *(ushortx4*)&th[(size_t)(n0 + n) * K + k0 + k4] = h;
    *(ushortx4*)&tl[(size_t)(n0 + n) * K + k0 + k4] = l;
  }
}

// ---------------------------- activation split ------------------------------
// fp32 [n] -> hi/lo bf16 bits, vectorized x4.
__global__ __launch_bounds__(256) void split_kernel(
    const float* __restrict__ in, unsigned short* __restrict__ hi,
    unsigned short* __restrict__ lo, int n4) {
  int i = blockIdx.x * 256 + threadIdx.x;
  if (i >= n4) return;
  float4 v = ((const float4*)in)[i];
  float f[4] = {v.x, v.y, v.z, v.w};
  ushortx4 h, l;
#pragma unroll
  for (int j = 0; j < 4; ++j) {
    unsigned short hb = f32_to_bf16(f[j]);
    h[j] = hb;
    l[j] = f32_to_bf16(f[j] - bf16_to_f32(hb));
  }
  ((ushortx4*)hi)[i] = h;
  ((ushortx4*)lo)[i] = l;
}

// ---------------------------- MFMA GEMM -------------------------------------
// C[M,N] = (Ahi+Alo)[M,K] @ (Bhi+Blo)^T[N,K]^T + bias, 3-pass hi/lo split.
// A,B given as bf16-bit ushort arrays; B is PRE-TRANSPOSED to [N,K].
// Tile 128x64, BK=32, 256 thr = 4 waves (2x2), wave tile 64x32 (4x2 frags).
#define GBM 128
#define GBN 64
#define GBK 32
#define LDSP 40   // padded K-stride in bf16 elems (80 B; 20-bank stride)

template <int RELU, int OUTBF16>
__global__ __launch_bounds__(256) void gemm_mfma_kernel(
    const unsigned short* __restrict__ Ahi, const unsigned short* __restrict__ Alo,
    const unsigned short* __restrict__ Bhi, const unsigned short* __restrict__ Blo,
    const float* __restrict__ bias, float* __restrict__ C,
    unsigned short* __restrict__ Chi, unsigned short* __restrict__ Clo,
    int M, int N, int K) {
  __shared__ unsigned short As[2][GBM][LDSP];
  __shared__ unsigned short Bs[2][GBN][LDSP];

  const int tid = threadIdx.x;
  const int wave = tid >> 6;
  const int lane = tid & 63;
  const int row0 = blockIdx.y * GBM;
  const int col0 = blockIdx.x * GBN;
  const int wr = (wave >> 1) * 64;   // wave row offset
  const int wc = (wave & 1) * 32;    // wave col offset
  const int lr = lane & 15;
  const int lk = (lane >> 4) * 8;

  const unsigned short* const ap[2] = {Ahi, Alo};
  const unsigned short* const bp[2] = {Bhi, Blo};

  // staging coords: A: r = tid>>2 (+64 for half 1), c = tid&3 (8 bf16 chunks)
  const int sr = tid >> 2;
  const int sc = (tid & 3) * 8;

  floatx4 acc[4][2];
#pragma unroll
  for (int i = 0; i < 4; ++i)
#pragma unroll
    for (int j = 0; j < 2; ++j) acc[i][j] = (floatx4)0.f;

  for (int k0 = 0; k0 < K; k0 += GBK) {
    ushortx8 a_st[2][2], b_st[2];
#pragma unroll
    for (int arr = 0; arr < 2; ++arr) {
#pragma unroll
      for (int half = 0; half < 2; ++half)
        a_st[arr][half] = *(const ushortx8*)(ap[arr] +
            (size_t)(row0 + sr + half * 64) * K + k0 + sc);
      b_st[arr] = *(const ushortx8*)(bp[arr] + (size_t)(col0 + sr) * K + k0 + sc);
    }
    __syncthreads();
#pragma unroll
    for (int arr = 0; arr < 2; ++arr) {
#pragma unroll
      for (int half = 0; half < 2; ++half)
        *(ushortx8*)&As[arr][sr + half * 64][sc] = a_st[arr][half];
      *(ushortx8*)&Bs[arr][sr][sc] = b_st[arr];
    }
    __syncthreads();

    shortx8 ah[4], al[4], bh[2], bl[2];
#pragma unroll
    for (int mi = 0; mi < 4; ++mi) {
      ah[mi] = *(const shortx8*)&As[0][wr + mi * 16 + lr][lk];
      al[mi] = *(const shortx8*)&As[1][wr + mi * 16 + lr][lk];
    }
#pragma unroll
    for (int ni = 0; ni < 2; ++ni) {
      bh[ni] = *(const shortx8*)&Bs[0][wc + ni * 16 + lr][lk];
      bl[ni] = *(const shortx8*)&Bs[1][wc + ni * 16 + lr][lk];
    }
#pragma unroll
    for (int mi = 0; mi < 4; ++mi)
#pragma unroll
      for (int ni = 0; ni < 2; ++ni) {
        acc[mi][ni] = __builtin_amdgcn_mfma_f32_16x16x32_bf16(
            ah[mi], bh[ni], acc[mi][ni], 0, 0, 0);
        acc[mi][ni] = __builtin_amdgcn_mfma_f32_16x16x32_bf16(
            al[mi], bh[ni], acc[mi][ni], 0, 0, 0);
        acc[mi][ni] = __builtin_amdgcn_mfma_f32_16x16x32_bf16(
            ah[mi], bl[ni], acc[mi][ni], 0, 0, 0);
      }
  }

  // epilogue: C/D layout col = lane&15, row = (lane>>4)*4 + reg
#pragma unroll
  for (int ni = 0; ni < 2; ++ni) {
    const int col = col0 + wc + ni * 16 + lr;
    const float bv = bias[col];
#pragma unroll
    for (int mi = 0; mi < 4; ++mi) {
      const int rowb = row0 + wr + mi * 16 + (lane >> 4) * 4;
#pragma unroll
      for (int j = 0; j < 4; ++j) {
        float val = acc[mi][ni][j] + bv;
        if (RELU) val = fmaxf(val, 0.f);
        const size_t idx = (size_t)(rowb + j) * N + col;
        if (OUTBF16) {
          unsigned short hb = f32_to_bf16(val);
          Chi[idx] = hb;
          Clo[idx] = f32_to_bf16(val - bf16_to_f32(hb));
        } else {
          C[idx] = val;
        }
      }
    }
  }
}

// ---------------------------- Attention (fp32, flash-style) ----------------
#define QB 64
#define KB 64

__global__ __launch_bounds__(256) void attn_kernel(
    const float* __restrict__ q, const float* __restrict__ k,
    const float* __restrict__ v, float* __restrict__ o) {
  __shared__ float Qs[QB][D_K + 4];
  __shared__ float Ks[KB][D_K + 4];
  __shared__ float Vs[KB][D_K + 4];
  __shared__ float Ps[QB][KB + 4];

  const int tid = threadIdx.x;
  const int qb = blockIdx.x;
  const int bh = blockIdx.y;
  const int b = bh >> 4;
  const int h = bh & 15;
  const size_t base = (size_t)b * SEQ * D_MODEL + (size_t)h * D_K;

  for (int idx = tid; idx < QB * (D_K / 4); idx += 256) {
    int r = idx >> 4, c4 = (idx & 15) << 2;
    *(float4*)&Qs[r][c4] =
        *(const float4*)&q[base + (size_t)(qb * QB + r) * D_MODEL + c4];
  }

  const int r = tid >> 2;
  const int c0 = (tid & 3) * 16;

  float acc[16] = {};
  float m = -1e30f, l = 0.f;
  const float scale = 0.125f;

  for (int kt = 0; kt < SEQ / KB; ++kt) {
    __syncthreads();
    for (int idx = tid; idx < KB * (D_K / 4); idx += 256) {
      int rr = idx >> 4, c4 = (idx & 15) << 2;
      size_t g = base + (size_t)(kt * KB + rr) * D_MODEL + c4;
      *(float4*)&Ks[rr][c4] = *(const float4*)&k[g];
      *(float4*)&Vs[rr][c4] = *(const float4*)&v[g];
    }
    __syncthreads();

    float s[16];
#pragma unroll
    for (int j = 0; j < 16; ++j) s[j] = 0.f;
#pragma unroll
    for (int d4 = 0; d4 < D_K; d4 += 4) {
      float4 qv = *(const float4*)&Qs[r][d4];
#pragma unroll
      for (int j = 0; j < 16; ++j) {
        float4 kv = *(const float4*)&Ks[c0 + j][d4];
        s[j] += qv.x * kv.x + qv.y * kv.y + qv.z * kv.z + qv.w * kv.w;
      }
    }
#pragma unroll
    for (int j = 0; j < 16; ++j) s[j] *= scale;

    float tmax = s[0];
#pragma unroll
    for (int j = 1; j < 16; ++j) tmax = fmaxf(tmax, s[j]);
    tmax = fmaxf(tmax, __shfl_xor(tmax, 1));
    tmax = fmaxf(tmax, __shfl_xor(tmax, 2));

    const float m_new = fmaxf(m, tmax);
    const float corr = __expf(m - m_new);
    float p[16], psum = 0.f;
#pragma unroll
    for (int j = 0; j < 16; ++j) { p[j] = __expf(s[j] - m_new); psum += p[j]; }
    psum += __shfl_xor(psum, 1);
    psum += __shfl_xor(psum, 2);
    l = l * corr + psum;
    m = m_new;
#pragma unroll
    for (int i = 0; i < 16; ++i) acc[i] *= corr;

    *(float4*)&Ps[r][c0 + 0] = make_float4(p[0], p[1], p[2], p[3]);
    *(float4*)&Ps[r][c0 + 4] = make_float4(p[4], p[5], p[6], p[7]);
    *(float4*)&Ps[r][c0 + 8] = make_float4(p[8], p[9], p[10], p[11]);
    *(float4*)&Ps[r][c0 + 12] = make_float4(p[12], p[13], p[14], p[15]);
    __syncthreads();

#pragma unroll 8
    for (int kc = 0; kc < KB; ++kc) {
      float pv = Ps[r][kc];
      float4 v0 = *(const float4*)&Vs[kc][c0 + 0];
      float4 v1 = *(const float4*)&Vs[kc][c0 + 4];
      float4 v2 = *(const float4*)&Vs[kc][c0 + 8];
      float4 v3 = *(const float4*)&Vs[kc][c0 + 12];
      acc[0] += pv * v0.x;  acc[1] += pv * v0.y;
      acc[2] += pv * v0.z;  acc[3] += pv * v0.w;
      acc[4] += pv * v1.x;  acc[5] += pv * v1.y;
      acc[6] += pv * v1.z;  acc[7] += pv * v1.w;
      acc[8] += pv * v2.x;  acc[9] += pv * v2.y;
      acc[10] += pv * v2.z; acc[11] += pv * v2.w;
      acc[12] += pv * v3.x; acc[13] += pv * v3.y;
      acc[14] += pv * v3.z; acc[15] += pv * v3.w;
    }
  }

  const float inv = 1.f / l;
  const size_t orow = base + (size_t)(qb * QB + r) * D_MODEL + c0;
  *(float4*)&o[orow + 0] = make_float4(acc[0]*inv, acc[1]*inv, acc[2]*inv, acc[3]*inv);
  *(float4*)&o[orow + 4] = make_float4(acc[4]*inv, acc[5]*inv, acc[6]*inv, acc[7]*inv);
  *(float4*)&o[orow + 8] = make_float4(acc[8]*inv, acc[9]*inv, acc[10]*inv, acc[11]*inv);
  *(float4*)&o[orow + 12] = make_float4(acc[12]*inv, acc[13]*inv, acc[14]*inv, acc[15]*inv);
}

// ---------------------------- Add + LayerNorm -------------------------------
__global__ __launch_bounds__(256) void add_ln_kernel(
    float* __restrict__ x, const float* __restrict__ t,
    const float* __restrict__ gamma, const float* __restrict__ beta) {
  const int row = blockIdx.x;
  const int tid = threadIdx.x;
  float* xrow = x + (size_t)row * D_MODEL;
  const float* trow = t + (size_t)row * D_MODEL;

  float4 xv = ((const float4*)xrow)[tid];
  float4 tv = ((const float4*)trow)[tid];
  float4 s;
  s.x = xv.x + tv.x; s.y = xv.y + tv.y;
  s.z = xv.z + tv.z; s.w = xv.w + tv.w;

  float sum = s.x + s.y + s.z + s.w;
  float sq = s.x * s.x + s.y * s.y + s.z * s.z + s.w * s.w;
#pragma unroll
  for (int off = 32; off > 0; off >>= 1) {
    sum += __shfl_down(sum, off);
    sq += __shfl_down(sq, off);
  }
  __shared__ float red[10];
  const int wave = tid >> 6;
  if ((tid & 63) == 0) { red[wave] = sum; red[wave + 4] = sq; }
  __syncthreads();
  if (tid == 0) {
    float S = red[0] + red[1] + red[2] + red[3];
    float Q = red[4] + red[5] + red[6] + red[7];
    float mu = S * (1.f / D_MODEL);
    float var = Q * (1.f / D_MODEL) - mu * mu;
    red[8] = mu;
    red[9] = rsqrtf(var + 1e-5f);
  }
  __syncthreads();
  const float mu = red[8], rstd = red[9];

  float4 gv = ((const float4*)gamma)[tid];
  float4 bv = ((const float4*)beta)[tid];
  float4 ov;
  ov.x = (s.x - mu) * rstd * gv.x + bv.x;
  ov.y = (s.y - mu) * rstd * gv.y + bv.y;
  ov.z = (s.z - mu) * rstd * gv.z + bv.z;
  ov.w = (s.w - mu) * rstd * gv.w + bv.w;
  ((float4*)xrow)[tid] = ov;
}

// ---------------------------- Launch ---------------------------------------
extern "C" void kernel_launch(void* const* d_in, const int* in_sizes, int n_in,
                              void* d_out, int out_size, void* d_ws,
                              size_t ws_size, hipStream_t stream) {
  const float* x  = (const float*)d_in[0];
  const float* Wq = (const float*)d_in[1];
  const float* bq = (const float*)d_in[2];
  const float* Wk = (const float*)d_in[3];
  const float* bk = (const float*)d_in[4];
  const float* Wv = (const float*)d_in[5];
  const float* bv = (const float*)d_in[6];
  const float* Wo = (const float*)d_in[7];
  const float* bo = (const float*)d_in[8];
  const float* W1 = (const float*)d_in[9];
  const float* b1 = (const float*)d_in[10];
  const float* W2 = (const float*)d_in[11];
  const float* b2 = (const float*)d_in[12];
  const float* g1 = (const float*)d_in[13];
  const float* be1 = (const float*)d_in[14];
  const float* g2 = (const float*)d_in[15];
  const float* be2 = (const float*)d_in[16];

  float* xb = (float*)d_out;               // residual stream (in place)
  char* ws = (char*)d_ws;
  const size_t MB = 1024ull * 1024ull;
  const size_t NTOK = (size_t)ROWS * D_MODEL;   // 4M elems

  // fp32 activation buffers
  float* qf = (float*)(ws + 0 * MB);
  float* kf = (float*)(ws + 16 * MB);
  float* vf = (float*)(ws + 32 * MB);
  float* of = (float*)(ws + 48 * MB);
  float* t0 = (float*)(ws + 64 * MB);
  // bf16 hi/lo activation buffers
  unsigned short* xh = (unsigned short*)(ws + 80 * MB);
  unsigned short* xl = (unsigned short*)(ws + 88 * MB);
  unsigned short* oh = (unsigned short*)(ws + 96 * MB);
  unsigned short* ol = (unsigned short*)(ws + 104 * MB);
  // h (FF hidden) hi/lo overlaps q/k/v/o region (dead by FF1)
  unsigned short* hh = (unsigned short*)(ws + 0 * MB);    // 32 MB
  unsigned short* hl = (unsigned short*)(ws + 32 * MB);   // 32 MB
  // transposed weights, per-layer
  unsigned short* wqh = (unsigned short*)(ws + 112 * MB);
  unsigned short* wql = (unsigned short*)(ws + 114 * MB);
  unsigned short* wkh = (unsigned short*)(ws + 116 * MB);
  unsigned short* wkl = (unsigned short*)(ws + 118 * MB);
  unsigned short* wvh = (unsigned short*)(ws + 120 * MB);
  unsigned short* wvl = (unsigned short*)(ws + 122 * MB);
  unsigned short* woh = (unsigned short*)(ws + 124 * MB);
  unsigned short* wol = (unsigned short*)(ws + 126 * MB);
  unsigned short* w1h = (unsigned short*)(ws + 128 * MB);
  unsigned short* w1l = (unsigned short*)(ws + 136 * MB);
  unsigned short* w2h = (unsigned short*)(ws + 144 * MB);
  unsigned short* w2l = (unsigned short*)(ws + 152 * MB);  // end: 160 MB

  hipMemcpyAsync(xb, x, NTOK * sizeof(float), hipMemcpyDeviceToDevice, stream);

  const dim3 blk(256);
  const dim3 g_dd(D_MODEL / GBN, ROWS / GBM);  // (16,32)
  const dim3 g_df(D_FF / GBN, ROWS / GBM);     // (64,32)
  const dim3 attn_grid(SEQ / QB, BATCH * N_HEAD);
  const dim3 ln_grid(ROWS);
  const int n4tok = (int)(NTOK / 4);
  const dim3 split_grid((n4tok + 255) / 256);

  for (int l = 0; l < LAYERS; ++l) {
    const float* Wq_l = Wq + (size_t)l * D_MODEL * D_MODEL;
    const float* Wk_l = Wk + (size_t)l * D_MODEL * D_MODEL;
    const float* Wv_l = Wv + (size_t)l * D_MODEL * D_MODEL;
    const float* Wo_l = Wo + (size_t)l * D_MODEL * D_MODEL;
    const float* W1_l = W1 + (size_t)l * D_MODEL * D_FF;
    const float* W2_l = W2 + (size_t)l * D_FF * D_MODEL;
    const float* bq_l = bq + (size_t)l * D_MODEL;
    const float* bk_l = bk + (size_t)l * D_MODEL;
    const float* bv_l = bv + (size_t)l * D_MODEL;
    const float* bo_l = bo + (size_t)l * D_MODEL;
    const float* b1_l = b1 + (size_t)l * D_FF;
    const float* b2_l = b2 + (size_t)l * D_MODEL;
    const float* g1_l = g1 + (size_t)l * D_MODEL;
    const float* be1_l = be1 + (size_t)l * D_MODEL;
    const float* g2_l = g2 + (size_t)l * D_MODEL;
    const float* be2_l = be2 + (size_t)l * D_MODEL;

    // weight prep
    wtrans_kernel<<<dim3(32, 32), blk, 0, stream>>>(Wq_l, wqh, wql, D_MODEL, D_MODEL);
    wtrans_kernel<<<dim3(32, 32), blk, 0, stream>>>(Wk_l, wkh, wkl, D_MODEL, D_MODEL);
    wtrans_kernel<<<dim3(32, 32), blk, 0, stream>>>(Wv_l, wvh, wvl, D_MODEL, D_MODEL);
    wtrans_kernel<<<dim3(32, 32), blk, 0, stream>>>(Wo_l, woh, wol, D_MODEL, D_MODEL);
    wtrans_kernel<<<dim3(32, 128), blk, 0, stream>>>(W1_l, w1h, w1l, D_MODEL, D_FF);
    wtrans_kernel<<<dim3(128, 32), blk, 0, stream>>>(W2_l, w2h, w2l, D_FF, D_MODEL);

    // QKV
    split_kernel<<<split_grid, blk, 0, stream>>>(xb, xh, xl, n4tok);
    gemm_mfma_kernel<0, 0><<<g_dd, blk, 0, stream>>>(
        xh, xl, wqh, wql, bq_l, qf, nullptr, nullptr, ROWS, D_MODEL, D_MODEL);
    gemm_mfma_kernel<0, 0><<<g_dd, blk, 0, stream>>>(
        xh, xl, wkh, wkl, bk_l, kf, nullptr, nullptr, ROWS, D_MODEL, D_MODEL);
    gemm_mfma_kernel<0, 0><<<g_dd, blk, 0, stream>>>(
        xh, xl, wvh, wvl, bv_l, vf, nullptr, nullptr, ROWS, D_MODEL, D_MODEL);

    attn_kernel<<<attn_grid, blk, 0, stream>>>(qf, kf, vf, of);

    // output projection + LN1
    split_kernel<<<split_grid, blk, 0, stream>>>(of, oh, ol, n4tok);
    gemm_mfma_kernel<0, 0><<<g_dd, blk, 0, stream>>>(
        oh, ol, woh, wol, bo_l, t0, nullptr, nullptr, ROWS, D_MODEL, D_MODEL);
    add_ln_kernel<<<ln_grid, blk, 0, stream>>>(xb, t0, g1_l, be1_l);

    // FFN
    split_kernel<<<split_grid, blk, 0, stream>>>(xb, xh, xl, n4tok);
    gemm_mfma_kernel<1, 1><<<g_df, blk, 0, stream>>>(
        xh, xl, w1h, w1l, b1_l, nullptr, hh, hl, ROWS, D_FF, D_MODEL);
    gemm_mfma_kernel<0, 0><<<g_dd, blk, 0, stream>>>(
        hh, hl, w2h, w2l, b2_l, t0, nullptr, nullptr, ROWS, D_MODEL, D_FF);
    add_ln_kernel<<<ln_grid, blk, 0, stream>>>(xb, t0, g2_l, be2_l);
  }
}

// Round 8
// 3992.186 us; speedup vs baseline: 1.7599x; 1.7599x over previous
//
#include <hip/hip_runtime.h>

// ---------------------------------------------------------------------------
// Transformer encoder, 6 layers, B=4 S=1024 D=1024 H=16 Dk=64 F=4096.
// Round 7 (= round 3 resubmit; broker timeouts): MFMA flash attention
// (hi/lo 3-pass) + fused hi/lo splits in producer epilogues, batched wtrans.
// GEMM kernel unchanged (validated round 2, ~770 TF effective).
// ---------------------------------------------------------------------------

#define D_MODEL 1024
#define N_HEAD 16
#define D_K 64
#define D_FF 4096
#define SEQ 1024
#define BATCH 4
#define ROWS (BATCH * SEQ)   // 4096
#define LAYERS 6

typedef __attribute__((ext_vector_type(4))) float floatx4;
typedef __attribute__((ext_vector_type(8))) short shortx8;
typedef __attribute__((ext_vector_type(8))) unsigned short ushortx8;
typedef __attribute__((ext_vector_type(4))) unsigned short ushortx4;

__device__ __forceinline__ unsigned short f32_to_bf16(float f) {
  unsigned int u = __float_as_uint(f);
  u = u + 0x7FFFu + ((u >> 16) & 1u);   // RNE
  return (unsigned short)(u >> 16);
}
__device__ __forceinline__ float bf16_to_f32(unsigned short s) {
  return __uint_as_float(((unsigned int)s) << 16);
}
__device__ __forceinline__ void split8(const float* f, shortx8& hi, shortx8& lo) {
#pragma unroll
  for (int j = 0; j < 8; ++j) {
    unsigned short hb = f32_to_bf16(f[j]);
    hi[j] = (short)hb;
    lo[j] = (short)f32_to_bf16(f[j] - bf16_to_f32(hb));
  }
}

// ---------------------------- weight transpose + split ----------------------
// src fp32 [K,N] row-major -> hi/lo bf16 [N,K] row-major.
__device__ __forceinline__ void wtrans_body(
    const float* __restrict__ W, unsigned short* __restrict__ th,
    unsigned short* __restrict__ tl, int K, int N, int k0, int n0) {
  __shared__ float tile[32][33];
  const int tid = threadIdx.x;
  {
    const int r = tid >> 3;
    const int c4 = (tid & 7) * 4;
    float4 v = *(const float4*)&W[(size_t)(k0 + r) * N + n0 + c4];
    tile[r][c4 + 0] = v.x; tile[r][c4 + 1] = v.y;
    tile[r][c4 + 2] = v.z; tile[r][c4 + 3] = v.w;
  }
  __syncthreads();
  {
    const int n = tid >> 3;
    const int k4 = (tid & 7) * 4;
    ushortx4 h, l;
#pragma unroll
    for (int j = 0; j < 4; ++j) {
      float f = tile[k4 + j][n];
      unsigned short hb = f32_to_bf16(f);
      h[j] = hb;
      l[j] = f32_to_bf16(f - bf16_to_f32(hb));
    }
    *(ushortx4*)&th[(size_t)(n0 + n) * K + k0 + k4] = h;
    *(ushortx4*)&tl[(size_t)(n0 + n) * K + k0 + k4] = l;
  }
}

__global__ __launch_bounds__(256) void wtrans_kernel(
    const float* __restrict__ W, unsigned short* __restrict__ th,
    unsigned short* __restrict__ tl, int K, int N) {
  wtrans_body(W, th, tl, K, N, blockIdx.x * 32, blockIdx.y * 32);
}

// batched over z = {Wq, Wk, Wv, Wo}, all D_MODEL x D_MODEL
__global__ __launch_bounds__(256) void wtrans_qkvo_kernel(
    const float* __restrict__ Wq, const float* __restrict__ Wk,
    const float* __restrict__ Wv, const float* __restrict__ Wo,
    unsigned short* __restrict__ qh, unsigned short* __restrict__ ql,
    unsigned short* __restrict__ kh, unsigned short* __restrict__ kl,
    unsigned short* __restrict__ vh, unsigned short* __restrict__ vl,
    unsigned short* __restrict__ oh, unsigned short* __restrict__ ol) {
  const float* W;
  unsigned short *th, *tl;
  switch (blockIdx.z) {
    case 0: W = Wq; th = qh; tl = ql; break;
    case 1: W = Wk; th = kh; tl = kl; break;
    case 2: W = Wv; th = vh; tl = vl; break;
    default: W = Wo; th = oh; tl = ol; break;
  }
  wtrans_body(W, th, tl, D_MODEL, D_MODEL, blockIdx.x * 32, blockIdx.y * 32);
}

// ---------------------------- activation split (input x only) ---------------
__global__ __launch_bounds__(256) void split_kernel(
    const float* __restrict__ in, unsigned short* __restrict__ hi,
    unsigned short* __restrict__ lo, int n4) {
  int i = blockIdx.x * 256 + threadIdx.x;
  if (i >= n4) return;
  float4 v = ((const float4*)in)[i];
  float f[4] = {v.x, v.y, v.z, v.w};
  ushortx4 h, l;
#pragma unroll
  for (int j = 0; j < 4; ++j) {
    unsigned short hb = f32_to_bf16(f[j]);
    h[j] = hb;
    l[j] = f32_to_bf16(f[j] - bf16_to_f32(hb));
  }
  ((ushortx4*)hi)[i] = h;
  ((ushortx4*)lo)[i] = l;
}

// ---------------------------- MFMA GEMM (unchanged, validated) --------------
#define GBM 128
#define GBN 64
#define GBK 32
#define LDSP 40

template <int RELU, int OUTBF16>
__global__ __launch_bounds__(256) void gemm_mfma_kernel(
    const unsigned short* __restrict__ Ahi, const unsigned short* __restrict__ Alo,
    const unsigned short* __restrict__ Bhi, const unsigned short* __restrict__ Blo,
    const float* __restrict__ bias, float* __restrict__ C,
    unsigned short* __restrict__ Chi, unsigned short* __restrict__ Clo,
    int M, int N, int K) {
  __shared__ unsigned short As[2][GBM][LDSP];
  __shared__ unsigned short Bs[2][GBN][LDSP];

  const int tid = threadIdx.x;
  const int wave = tid >> 6;
  const int lane = tid & 63;
  const int row0 = blockIdx.y * GBM;
  const int col0 = blockIdx.x * GBN;
  const int wr = (wave >> 1) * 64;
  const int wc = (wave & 1) * 32;
  const int lr = lane & 15;
  const int lk = (lane >> 4) * 8;

  const unsigned short* const ap[2] = {Ahi, Alo};
  const unsigned short* const bp[2] = {Bhi, Blo};

  const int sr = tid >> 2;
  const int sc = (tid & 3) * 8;

  floatx4 acc[4][2];
#pragma unroll
  for (int i = 0; i < 4; ++i)
#pragma unroll
    for (int j = 0; j < 2; ++j) acc[i][j] = (floatx4)0.f;

  for (int k0 = 0; k0 < K; k0 += GBK) {
    ushortx8 a_st[2][2], b_st[2];
#pragma unroll
    for (int arr = 0; arr < 2; ++arr) {
#pragma unroll
      for (int half = 0; half < 2; ++half)
        a_st[arr][half] = *(const ushortx8*)(ap[arr] +
            (size_t)(row0 + sr + half * 64) * K + k0 + sc);
      b_st[arr] = *(const ushortx8*)(bp[arr] + (size_t)(col0 + sr) * K + k0 + sc);
    }
    __syncthreads();
#pragma unroll
    for (int arr = 0; arr < 2; ++arr) {
#pragma unroll
      for (int half = 0; half < 2; ++half)
        *(ushortx8*)&As[arr][sr + half * 64][sc] = a_st[arr][half];
      *(ushortx8*)&Bs[arr][sr][sc] = b_st[arr];
    }
    __syncthreads();

    shortx8 ah[4], al[4], bh[2], bl[2];
#pragma unroll
    for (int mi = 0; mi < 4; ++mi) {
      ah[mi] = *(const shortx8*)&As[0][wr + mi * 16 + lr][lk];
      al[mi] = *(const shortx8*)&As[1][wr + mi * 16 + lr][lk];
    }
#pragma unroll
    for (int ni = 0; ni < 2; ++ni) {
      bh[ni] = *(const shortx8*)&Bs[0][wc + ni * 16 + lr][lk];
      bl[ni] = *(const shortx8*)&Bs[1][wc + ni * 16 + lr][lk];
    }
#pragma unroll
    for (int mi = 0; mi < 4; ++mi)
#pragma unroll
      for (int ni = 0; ni < 2; ++ni) {
        acc[mi][ni] = __builtin_amdgcn_mfma_f32_16x16x32_bf16(
            ah[mi], bh[ni], acc[mi][ni], 0, 0, 0);
        acc[mi][ni] = __builtin_amdgcn_mfma_f32_16x16x32_bf16(
            al[mi], bh[ni], acc[mi][ni], 0, 0, 0);
        acc[mi][ni] = __builtin_amdgcn_mfma_f32_16x16x32_bf16(
            ah[mi], bl[ni], acc[mi][ni], 0, 0, 0);
      }
  }

#pragma unroll
  for (int ni = 0; ni < 2; ++ni) {
    const int col = col0 + wc + ni * 16 + lr;
    const float bv = bias[col];
#pragma unroll
    for (int mi = 0; mi < 4; ++mi) {
      const int rowb = row0 + wr + mi * 16 + (lane >> 4) * 4;
#pragma unroll
      for (int j = 0; j < 4; ++j) {
        float val = acc[mi][ni][j] + bv;
        if (RELU) val = fmaxf(val, 0.f);
        const size_t idx = (size_t)(rowb + j) * N + col;
        if (OUTBF16) {
          unsigned short hb = f32_to_bf16(val);
          Chi[idx] = hb;
          Clo[idx] = f32_to_bf16(val - bf16_to_f32(hb));
        } else {
          C[idx] = val;
        }
      }
    }
  }
}

// ---------------------------- MFMA flash attention --------------------------
// One block per (qblock, b*h). 4 waves x 16 Q-rows = QB 64. KB = 64.
// K LDS [kk][d], V LDS transposed [d][kk], hi/lo bf16, XOR 16B-block swizzle.
// Output written directly as hi/lo bf16 (feeds Wo GEMM).
#define QB 64
#define KB 64

__global__ __launch_bounds__(256) void attn_mfma_kernel(
    const float* __restrict__ q, const float* __restrict__ k,
    const float* __restrict__ v, unsigned short* __restrict__ ohi,
    unsigned short* __restrict__ olo) {
  __shared__ unsigned short Kh[64 * 64], Kl[64 * 64];
  __shared__ unsigned short Vh[64 * 64], Vl[64 * 64];   // transposed [d][kk]
  __shared__ unsigned short Ph[4][16 * 64], Pl[4][16 * 64];

  const int tid = threadIdx.x;
  const int w = tid >> 6;
  const int l = tid & 63;
  const int lr = l & 15;
  const int lg = l >> 4;
  const int qb = blockIdx.x;
  const int bh = blockIdx.y;
  const int b = bh >> 4;
  const int h = bh & 15;
  const size_t base = (size_t)b * SEQ * D_MODEL + (size_t)h * D_K;

  // Q fragments (A-layout: row=lr, k=8*lg+j), 1/sqrt(dk)=0.125 folded (exact)
  shortx8 Qh[2], Ql[2];
  {
    const float* qrow = q + base + (size_t)(qb * QB + w * 16 + lr) * D_MODEL;
#pragma unroll
    for (int s = 0; s < 2; ++s) {
      float f[8];
      *(float4*)&f[0] = *(const float4*)&qrow[s * 32 + lg * 8];
      *(float4*)&f[4] = *(const float4*)&qrow[s * 32 + lg * 8 + 4];
#pragma unroll
      for (int j = 0; j < 8; ++j) f[j] *= 0.125f;
      split8(f, Qh[s], Ql[s]);
    }
  }

  floatx4 acc_o[4];
#pragma unroll
  for (int i = 0; i < 4; ++i) acc_o[i] = (floatx4)0.f;
  float m_run[4] = {-1e30f, -1e30f, -1e30f, -1e30f};
  float l_run[4] = {0.f, 0.f, 0.f, 0.f};

  for (int kt = 0; kt < SEQ / KB; ++kt) {
    __syncthreads();
    // stage K: [kk][d] swizzled
#pragma unroll
    for (int it = 0; it < 2; ++it) {
      const int idx = tid + it * 256;
      const int kk = idx >> 3, dblk = idx & 7;
      const float* kr = k + base + (size_t)(kt * KB + kk) * D_MODEL + dblk * 8;
      float f[8];
      *(float4*)&f[0] = *(const float4*)kr;
      *(float4*)&f[4] = *(const float4*)(kr + 4);
      shortx8 hi, lo;
      split8(f, hi, lo);
      const int a = kk * 64 + ((dblk ^ (kk & 7)) * 8);
      *(shortx8*)&Kh[a] = hi;
      *(shortx8*)&Kl[a] = lo;
    }
    // stage V transposed: [d][kk] swizzled; coalesced row reads
#pragma unroll
    for (int it = 0; it < 2; ++it) {
      const int g = w + it * 4;
      const int d = l;
      float f[8];
#pragma unroll
      for (int j = 0; j < 8; ++j)
        f[j] = v[base + (size_t)(kt * KB + g * 8 + j) * D_MODEL + d];
      shortx8 hi, lo;
      split8(f, hi, lo);
      const int a = d * 64 + ((g ^ (d & 7)) * 8);
      *(shortx8*)&Vh[a] = hi;
      *(shortx8*)&Vl[a] = lo;
    }
    __syncthreads();

    // S = Q*K^T (hi/lo 3-pass)
    floatx4 sfr[4];
#pragma unroll
    for (int f = 0; f < 4; ++f) {
      floatx4 acc = (floatx4)0.f;
      const int kk = f * 16 + lr;
#pragma unroll
      for (int s = 0; s < 2; ++s) {
        const int a = kk * 64 + (((s * 4 + lg) ^ (kk & 7)) * 8);
        shortx8 kbh = *(const shortx8*)&Kh[a];
        shortx8 kbl = *(const shortx8*)&Kl[a];
        acc = __builtin_amdgcn_mfma_f32_16x16x32_bf16(Qh[s], kbh, acc, 0, 0, 0);
        acc = __builtin_amdgcn_mfma_f32_16x16x32_bf16(Ql[s], kbh, acc, 0, 0, 0);
        acc = __builtin_amdgcn_mfma_f32_16x16x32_bf16(Qh[s], kbl, acc, 0, 0, 0);
      }
      sfr[f] = acc;
    }

    // online softmax: D layout row=(lg*4+j), col=f*16+lr
    float corr[4];
#pragma unroll
    for (int j = 0; j < 4; ++j) {
      float tm = fmaxf(fmaxf(sfr[0][j], sfr[1][j]), fmaxf(sfr[2][j], sfr[3][j]));
      tm = fmaxf(tm, __shfl_xor(tm, 1));
      tm = fmaxf(tm, __shfl_xor(tm, 2));
      tm = fmaxf(tm, __shfl_xor(tm, 4));
      tm = fmaxf(tm, __shfl_xor(tm, 8));
      const float mn = fmaxf(m_run[j], tm);
      corr[j] = __expf(m_run[j] - mn);
      m_run[j] = mn;
      float ps = 0.f;
#pragma unroll
      for (int f = 0; f < 4; ++f) {
        float p = __expf(sfr[f][j] - mn);
        sfr[f][j] = p;
        ps += p;
      }
      ps += __shfl_xor(ps, 1);
      ps += __shfl_xor(ps, 2);
      ps += __shfl_xor(ps, 4);
      ps += __shfl_xor(ps, 8);
      l_run[j] = l_run[j] * corr[j] + ps;
#pragma unroll
      for (int nf = 0; nf < 4; ++nf) acc_o[nf][j] *= corr[j];
    }

    // P -> per-wave LDS (hi/lo, swizzled)
    unsigned short* phw = &Ph[w][0];
    unsigned short* plw = &Pl[w][0];
#pragma unroll
    for (int f = 0; f < 4; ++f) {
      const int kk = f * 16 + lr;
      const int blk = kk >> 3;
      const int within = kk & 7;
#pragma unroll
      for (int j = 0; j < 4; ++j) {
        const int qr = lg * 4 + j;
        const float p = sfr[f][j];
        const unsigned short hb = f32_to_bf16(p);
        const int a = qr * 64 + ((blk ^ (qr & 7)) * 8) + within;
        phw[a] = hb;
        plw[a] = f32_to_bf16(p - bf16_to_f32(hb));
      }
    }

    // O += P*V (hi/lo 3-pass)
#pragma unroll
    for (int s2 = 0; s2 < 2; ++s2) {
      const int blk = (s2 * 4 + lg) ^ (lr & 7);
      shortx8 pah = *(const shortx8*)&Ph[w][lr * 64 + blk * 8];
      shortx8 pal = *(const shortx8*)&Pl[w][lr * 64 + blk * 8];
#pragma unroll
      for (int nf = 0; nf < 4; ++nf) {
        const int d = nf * 16 + lr;
        const int a = d * 64 + blk * 8;   // (d&7)==(lr&7) -> same swizzle
        shortx8 vbh = *(const shortx8*)&Vh[a];
        shortx8 vbl = *(const shortx8*)&Vl[a];
        acc_o[nf] = __builtin_amdgcn_mfma_f32_16x16x32_bf16(pah, vbh, acc_o[nf], 0, 0, 0);
        acc_o[nf] = __builtin_amdgcn_mfma_f32_16x16x32_bf16(pal, vbh, acc_o[nf], 0, 0, 0);
        acc_o[nf] = __builtin_amdgcn_mfma_f32_16x16x32_bf16(pah, vbl, acc_o[nf], 0, 0, 0);
      }
    }
  }

  // epilogue: O/l written directly as hi/lo bf16
  float inv[4];
#pragma unroll
  for (int j = 0; j < 4; ++j) inv[j] = 1.f / l_run[j];
#pragma unroll
  for (int nf = 0; nf < 4; ++nf) {
    const int d = nf * 16 + lr;
#pragma unroll
    for (int j = 0; j < 4; ++j) {
      const int qr = lg * 4 + j;
      const float val = acc_o[nf][j] * inv[j];
      const size_t idx = base + (size_t)(qb * QB + w * 16 + qr) * D_MODEL + d;
      const unsigned short hb = f32_to_bf16(val);
      ohi[idx] = hb;
      olo[idx] = f32_to_bf16(val - bf16_to_f32(hb));
    }
  }
}

// ---------------------------- Add + LayerNorm (+ fused hi/lo split) ---------
__global__ __launch_bounds__(256) void add_ln_kernel(
    float* __restrict__ x, const float* __restrict__ t,
    const float* __restrict__ gamma, const float* __restrict__ beta,
    unsigned short* __restrict__ xh, unsigned short* __restrict__ xl) {
  const int row = blockIdx.x;
  const int tid = threadIdx.x;
  float* xrow = x + (size_t)row * D_MODEL;
  const float* trow = t + (size_t)row * D_MODEL;

  float4 xv = ((const float4*)xrow)[tid];
  float4 tv = ((const float4*)trow)[tid];
  float4 s;
  s.x = xv.x + tv.x; s.y = xv.y + tv.y;
  s.z = xv.z + tv.z; s.w = xv.w + tv.w;

  float sum = s.x + s.y + s.z + s.w;
  float sq = s.x * s.x + s.y * s.y + s.z * s.z + s.w * s.w;
#pragma unroll
  for (int off = 32; off > 0; off >>= 1) {
    sum += __shfl_down(sum, off);
    sq += __shfl_down(sq, off);
  }
  __shared__ float red[10];
  const int wave = tid >> 6;
  if ((tid & 63) == 0) { red[wave] = sum; red[wave + 4] = sq; }
  __syncthreads();
  if (tid == 0) {
    float S = red[0] + red[1] + red[2] + red[3];
    float Q = red[4] + red[5] + red[6] + red[7];
    float mu = S * (1.f / D_MODEL);
    float var = Q * (1.f / D_MODEL) - mu * mu;
    red[8] = mu;
    red[9] = rsqrtf(var + 1e-5f);
  }
  __syncthreads();
  const float mu = red[8], rstd = red[9];

  float4 gv = ((const float4*)gamma)[tid];
  float4 bv = ((const float4*)beta)[tid];
  float f[4];
  f[0] = (s.x - mu) * rstd * gv.x + bv.x;
  f[1] = (s.y - mu) * rstd * gv.y + bv.y;
  f[2] = (s.z - mu) * rstd * gv.z + bv.z;
  f[3] = (s.w - mu) * rstd * gv.w + bv.w;
  ((float4*)xrow)[tid] = make_float4(f[0], f[1], f[2], f[3]);

  ushortx4 h4, l4;
#pragma unroll
  for (int j = 0; j < 4; ++j) {
    unsigned short hb = f32_to_bf16(f[j]);
    h4[j] = hb;
    l4[j] = f32_to_bf16(f[j] - bf16_to_f32(hb));
  }
  const size_t o4 = (size_t)row * (D_MODEL / 4) + tid;
  ((ushortx4*)xh)[o4] = h4;
  ((ushortx4*)xl)[o4] = l4;
}

// ---------------------------- Launch ---------------------------------------
extern "C" void kernel_launch(void* const* d_in, const int* in_sizes, int n_in,
                              void* d_out, int out_size, void* d_ws,
                              size_t ws_size, hipStream_t stream) {
  const float* x  = (const float*)d_in[0];
  const float* Wq = (const float*)d_in[1];
  const float* bq = (const float*)d_in[2];
  const float* Wk = (const float*)d_in[3];
  const float* bk = (const float*)d_in[4];
  const float* Wv = (const float*)d_in[5];
  const float* bv = (const float*)d_in[6];
  const float* Wo = (const float*)d_in[7];
  const float* bo = (const float*)d_in[8];
  const float* W1 = (const float*)d_in[9];
  const float* b1 = (const float*)d_in[10];
  const float* W2 = (const float*)d_in[11];
  const float* b2 = (const float*)d_in[12];
  const float* g1 = (const float*)d_in[13];
  const float* be1 = (const float*)d_in[14];
  const float* g2 = (const float*)d_in[15];
  const float* be2 = (const float*)d_in[16];

  float* xb = (float*)d_out;               // residual stream (in place)
  char* ws = (char*)d_ws;
  const size_t MB = 1024ull * 1024ull;
  const size_t NTOK = (size_t)ROWS * D_MODEL;

  // activations
  float* qf = (float*)(ws + 0 * MB);       // 16 MB
  float* kf = (float*)(ws + 16 * MB);      // 16 MB
  float* vf = (float*)(ws + 32 * MB);      // 16 MB
  float* t0 = (float*)(ws + 64 * MB);      // 16 MB
  unsigned short* xh = (unsigned short*)(ws + 80 * MB);   // 8 MB
  unsigned short* xl = (unsigned short*)(ws + 88 * MB);   // 8 MB
  unsigned short* oh = (unsigned short*)(ws + 96 * MB);   // 8 MB
  unsigned short* ol = (unsigned short*)(ws + 104 * MB);  // 8 MB
  // FF hidden hi/lo overlaps q/k/v (dead after attention)
  unsigned short* hh = (unsigned short*)(ws + 0 * MB);    // 32 MB
  unsigned short* hl = (unsigned short*)(ws + 32 * MB);   // 32 MB
  // transposed weights (per layer)
  unsigned short* wqh = (unsigned short*)(ws + 112 * MB);
  unsigned short* wql = (unsigned short*)(ws + 114 * MB);
  unsigned short* wkh = (unsigned short*)(ws + 116 * MB);
  unsigned short* wkl = (unsigned short*)(ws + 118 * MB);
  unsigned short* wvh = (unsigned short*)(ws + 120 * MB);
  unsigned short* wvl = (unsigned short*)(ws + 122 * MB);
  unsigned short* woh = (unsigned short*)(ws + 124 * MB);
  unsigned short* wol = (unsigned short*)(ws + 126 * MB);
  unsigned short* w1h = (unsigned short*)(ws + 128 * MB);
  unsigned short* w1l = (unsigned short*)(ws + 136 * MB);
  unsigned short* w2h = (unsigned short*)(ws + 144 * MB);
  unsigned short* w2l = (unsigned short*)(ws + 152 * MB);  // end 160 MB

  hipMemcpyAsync(xb, x, NTOK * sizeof(float), hipMemcpyDeviceToDevice, stream);

  const dim3 blk(256);
  const dim3 g_dd(D_MODEL / GBN, ROWS / GBM);
  const dim3 g_df(D_FF / GBN, ROWS / GBM);
  const dim3 attn_grid(SEQ / QB, BATCH * N_HEAD);
  const dim3 ln_grid(ROWS);
  const int n4tok = (int)(NTOK / 4);

  // initial x -> hi/lo (layers 1+ get xh/xl from add_ln2)
  split_kernel<<<dim3((n4tok + 255) / 256), blk, 0, stream>>>(xb, xh, xl, n4tok);

  for (int l = 0; l < LAYERS; ++l) {
    const float* Wq_l = Wq + (size_t)l * D_MODEL * D_MODEL;
    const float* Wk_l = Wk + (size_t)l * D_MODEL * D_MODEL;
    const float* Wv_l = Wv + (size_t)l * D_MODEL * D_MODEL;
    const float* Wo_l = Wo + (size_t)l * D_MODEL * D_MODEL;
    const float* W1_l = W1 + (size_t)l * D_MODEL * D_FF;
    const float* W2_l = W2 + (size_t)l * D_FF * D_MODEL;
    const float* bq_l = bq + (size_t)l * D_MODEL;
    const float* bk_l = bk + (size_t)l * D_MODEL;
    const float* bv_l = bv + (size_t)l * D_MODEL;
    const float* bo_l = bo + (size_t)l * D_MODEL;
    const float* b1_l = b1 + (size_t)l * D_FF;
    const float* b2_l = b2 + (size_t)l * D_MODEL;
    const float* g1_l = g1 + (size_t)l * D_MODEL;
    const float* be1_l = be1 + (size_t)l * D_MODEL;
    const float* g2_l = g2 + (size_t)l * D_MODEL;
    const float* be2_l = be2 + (size_t)l * D_MODEL;

    wtrans_qkvo_kernel<<<dim3(32, 32, 4), blk, 0, stream>>>(
        Wq_l, Wk_l, Wv_l, Wo_l, wqh, wql, wkh, wkl, wvh, wvl, woh, wol);
    wtrans_kernel<<<dim3(32, 128), blk, 0, stream>>>(W1_l, w1h, w1l, D_MODEL, D_FF);
    wtrans_kernel<<<dim3(128, 32), blk, 0, stream>>>(W2_l, w2h, w2l, D_FF, D_MODEL);

    gemm_mfma_kernel<0, 0><<<g_dd, blk, 0, stream>>>(
        xh, xl, wqh, wql, bq_l, qf, nullptr, nullptr, ROWS, D_MODEL, D_MODEL);
    gemm_mfma_kernel<0, 0><<<g_dd, blk, 0, stream>>>(
        xh, xl, wkh, wkl, bk_l, kf, nullptr, nullptr, ROWS, D_MODEL, D_MODEL);
    gemm_mfma_kernel<0, 0><<<g_dd, blk, 0, stream>>>(
        xh, xl, wvh, wvl, bv_l, vf, nullptr, nullptr, ROWS, D_MODEL, D_MODEL);

    attn_mfma_kernel<<<attn_grid, blk, 0, stream>>>(qf, kf, vf, oh, ol);

    gemm_mfma_kernel<0, 0><<<g_dd, blk, 0, stream>>>(
        oh, ol, woh, wol, bo_l, t0, nullptr, nullptr, ROWS, D_MODEL, D_MODEL);
    add_ln_kernel<<<ln_grid, blk, 0, stream>>>(xb, t0, g1_l, be1_l, xh, xl);

    gemm_mfma_kernel<1, 1><<<g_df, blk, 0, stream>>>(
        xh, xl, w1h, w1l, b1_l, nullptr, hh, hl, ROWS, D_FF, D_MODEL);
    gemm_mfma_kernel<0, 0><<<g_dd, blk, 0, stream>>>(
        hh, hl, w2h, w2l, b2_l, t0, nullptr, nullptr, ROWS, D_MODEL, D_FF);
    add_ln_kernel<<<ln_grid, blk, 0, stream>>>(xb, t0, g2_l, be2_l, xh, xl);
  }
}

// Round 9
// 3700.781 us; speedup vs baseline: 1.8985x; 1.0787x over previous
//
#include <hip/hip_runtime.h>

// ---------------------------------------------------------------------------
// Transformer encoder, 6 layers, B=4 S=1024 D=1024 H=16 Dk=64 F=4096.
// Round 9: GEMM staging moved to global_load_lds (width=16, linear LDS,
// m97 structure) + XCD-aware block swizzle. Attention/LN unchanged (R8-valid).
// ---------------------------------------------------------------------------

#define D_MODEL 1024
#define N_HEAD 16
#define D_K 64
#define D_FF 4096
#define SEQ 1024
#define BATCH 4
#define ROWS (BATCH * SEQ)   // 4096
#define LAYERS 6

typedef __attribute__((ext_vector_type(4))) float floatx4;
typedef __attribute__((ext_vector_type(8))) short shortx8;
typedef __attribute__((ext_vector_type(8))) unsigned short ushortx8;
typedef __attribute__((ext_vector_type(4))) unsigned short ushortx4;

typedef const __attribute__((address_space(1))) unsigned int ga_u32;
typedef __attribute__((address_space(3))) unsigned int lds_u32;
#define GLD16(gp, lp) __builtin_amdgcn_global_load_lds( \
    (ga_u32*)(gp), (lds_u32*)(lp), 16, 0, 0)

__device__ __forceinline__ unsigned short f32_to_bf16(float f) {
  unsigned int u = __float_as_uint(f);
  u = u + 0x7FFFu + ((u >> 16) & 1u);   // RNE
  return (unsigned short)(u >> 16);
}
__device__ __forceinline__ float bf16_to_f32(unsigned short s) {
  return __uint_as_float(((unsigned int)s) << 16);
}
__device__ __forceinline__ void split8(const float* f, shortx8& hi, shortx8& lo) {
#pragma unroll
  for (int j = 0; j < 8; ++j) {
    unsigned short hb = f32_to_bf16(f[j]);
    hi[j] = (short)hb;
    lo[j] = (short)f32_to_bf16(f[j] - bf16_to_f32(hb));
  }
}

// ---------------------------- weight transpose + split ----------------------
// src fp32 [K,N] row-major -> hi/lo bf16 [N,K] row-major.
__device__ __forceinline__ void wtrans_body(
    const float* __restrict__ W, unsigned short* __restrict__ th,
    unsigned short* __restrict__ tl, int K, int N, int k0, int n0) {
  __shared__ float tile[32][33];
  const int tid = threadIdx.x;
  {
    const int r = tid >> 3;
    const int c4 = (tid & 7) * 4;
    float4 v = *(const float4*)&W[(size_t)(k0 + r) * N + n0 + c4];
    tile[r][c4 + 0] = v.x; tile[r][c4 + 1] = v.y;
    tile[r][c4 + 2] = v.z; tile[r][c4 + 3] = v.w;
  }
  __syncthreads();
  {
    const int n = tid >> 3;
    const int k4 = (tid & 7) * 4;
    ushortx4 h, l;
#pragma unroll
    for (int j = 0; j < 4; ++j) {
      float f = tile[k4 + j][n];
      unsigned short hb = f32_to_bf16(f);
      h[j] = hb;
      l[j] = f32_to_bf16(f - bf16_to_f32(hb));
    }
    *(ushortx4*)&th[(size_t)(n0 + n) * K + k0 + k4] = h;
    *(ushortx4*)&tl[(size_t)(n0 + n) * K + k0 + k4] = l;
  }
}

__global__ __launch_bounds__(256) void wtrans_kernel(
    const float* __restrict__ W, unsigned short* __restrict__ th,
    unsigned short* __restrict__ tl, int K, int N) {
  wtrans_body(W, th, tl, K, N, blockIdx.x * 32, blockIdx.y * 32);
}

// batched over z = {Wq, Wk, Wv, Wo}, all D_MODEL x D_MODEL
__global__ __launch_bounds__(256) void wtrans_qkvo_kernel(
    const float* __restrict__ Wq, const float* __restrict__ Wk,
    const float* __restrict__ Wv, const float* __restrict__ Wo,
    unsigned short* __restrict__ qh, unsigned short* __restrict__ ql,
    unsigned short* __restrict__ kh, unsigned short* __restrict__ kl,
    unsigned short* __restrict__ vh, unsigned short* __restrict__ vl,
    unsigned short* __restrict__ oh, unsigned short* __restrict__ ol) {
  const float* W;
  unsigned short *th, *tl;
  switch (blockIdx.z) {
    case 0: W = Wq; th = qh; tl = ql; break;
    case 1: W = Wk; th = kh; tl = kl; break;
    case 2: W = Wv; th = vh; tl = vl; break;
    default: W = Wo; th = oh; tl = ol; break;
  }
  wtrans_body(W, th, tl, D_MODEL, D_MODEL, blockIdx.x * 32, blockIdx.y * 32);
}

// ---------------------------- activation split (input x only) ---------------
__global__ __launch_bounds__(256) void split_kernel(
    const float* __restrict__ in, unsigned short* __restrict__ hi,
    unsigned short* __restrict__ lo, int n4) {
  int i = blockIdx.x * 256 + threadIdx.x;
  if (i >= n4) return;
  float4 v = ((const float4*)in)[i];
  float f[4] = {v.x, v.y, v.z, v.w};
  ushortx4 h, l;
#pragma unroll
  for (int j = 0; j < 4; ++j) {
    unsigned short hb = f32_to_bf16(f[j]);
    h[j] = hb;
    l[j] = f32_to_bf16(f[j] - bf16_to_f32(hb));
  }
  ((ushortx4*)hi)[i] = h;
  ((ushortx4*)lo)[i] = l;
}

// ---------------------------- MFMA GEMM (global_load_lds staging) -----------
// C[M,N] = (Ahi+Alo) @ (Bhi+Blo)^T + bias, 3-pass hi/lo. B pre-transposed [N,K].
// Tile 128x64, BK=32, 4 waves (2x2). LDS linear [row][32] bf16, no padding
// (global_load_lds requires linear dest: uniform base + lane*16B — rule #21
// linear-both-sides). 6 gload/wave/K-step: A rows 32w..+31 (hi,lo), B rows
// 16w..+15 (hi,lo). Two barriers per K-step (m97 structure).
#define GBM 128
#define GBN 64
#define GBK 32

template <int RELU, int OUTBF16>
__global__ __launch_bounds__(256) void gemm_mfma_kernel(
    const unsigned short* __restrict__ Ahi, const unsigned short* __restrict__ Alo,
    const unsigned short* __restrict__ Bhi, const unsigned short* __restrict__ Blo,
    const float* __restrict__ bias, float* __restrict__ C,
    unsigned short* __restrict__ Chi, unsigned short* __restrict__ Clo,
    int M, int N, int K) {
  __shared__ unsigned short AsH[GBM * GBK];
  __shared__ unsigned short AsL[GBM * GBK];
  __shared__ unsigned short BsH[GBN * GBK];
  __shared__ unsigned short BsL[GBN * GBK];

  const int tid = threadIdx.x;
  const int wave = tid >> 6;
  const int lane = tid & 63;

  // XCD-aware swizzle: contiguous chunk of blocks per XCD (nwg % 8 == 0:
  // QKVO/FF2 grid 16x32=512, FF1 grid 64x32=2048).
  const int gx = gridDim.x;
  const int nwg = gx * gridDim.y;
  const int flat = blockIdx.y * gx + blockIdx.x;
  const int swz = (flat & 7) * (nwg >> 3) + (flat >> 3);
  const int row0 = (swz / gx) * GBM;
  const int col0 = (swz % gx) * GBN;

  const int wr = (wave >> 1) * 64;   // wave row offset
  const int wc = (wave & 1) * 32;    // wave col offset
  const int lr = lane & 15;
  const int lk = (lane >> 4) * 8;

  // staging: lane -> (row-in-16-row-segment, 16B chunk); 4 lanes/row
  const int rl = lane >> 2;          // 0..15
  const int ce = (lane & 3) * 8;     // elem offset 0,8,16,24

  const size_t aoff0 = (size_t)(row0 + 32 * wave + rl) * K + ce;
  const size_t aoff1 = aoff0 + (size_t)16 * K;
  const size_t boff  = (size_t)(col0 + 16 * wave + rl) * K + ce;
  unsigned short* const asd0 = AsH + (32 * wave) * GBK;
  unsigned short* const asd1 = AsH + (32 * wave + 16) * GBK;
  unsigned short* const ald0 = AsL + (32 * wave) * GBK;
  unsigned short* const ald1 = AsL + (32 * wave + 16) * GBK;
  unsigned short* const bsd  = BsH + (16 * wave) * GBK;
  unsigned short* const bld  = BsL + (16 * wave) * GBK;

  floatx4 acc[4][2];
#pragma unroll
  for (int i = 0; i < 4; ++i)
#pragma unroll
    for (int j = 0; j < 2; ++j) acc[i][j] = (floatx4)0.f;

  for (int k0 = 0; k0 < K; k0 += GBK) {
    __syncthreads();               // previous tile fully consumed
    GLD16(Ahi + aoff0 + k0, asd0);
    GLD16(Ahi + aoff1 + k0, asd1);
    GLD16(Alo + aoff0 + k0, ald0);
    GLD16(Alo + aoff1 + k0, ald1);
    GLD16(Bhi + boff + k0, bsd);
    GLD16(Blo + boff + k0, bld);
    __syncthreads();               // vmcnt(0) drained -> tile ready

    shortx8 ah[4], al[4], bh[2], bl[2];
#pragma unroll
    for (int mi = 0; mi < 4; ++mi) {
      ah[mi] = *(const shortx8*)&AsH[(wr + mi * 16 + lr) * GBK + lk];
      al[mi] = *(const shortx8*)&AsL[(wr + mi * 16 + lr) * GBK + lk];
    }
#pragma unroll
    for (int ni = 0; ni < 2; ++ni) {
      bh[ni] = *(const shortx8*)&BsH[(wc + ni * 16 + lr) * GBK + lk];
      bl[ni] = *(const shortx8*)&BsL[(wc + ni * 16 + lr) * GBK + lk];
    }
#pragma unroll
    for (int mi = 0; mi < 4; ++mi)
#pragma unroll
      for (int ni = 0; ni < 2; ++ni) {
        acc[mi][ni] = __builtin_amdgcn_mfma_f32_16x16x32_bf16(
            ah[mi], bh[ni], acc[mi][ni], 0, 0, 0);
        acc[mi][ni] = __builtin_amdgcn_mfma_f32_16x16x32_bf16(
            al[mi], bh[ni], acc[mi][ni], 0, 0, 0);
        acc[mi][ni] = __builtin_amdgcn_mfma_f32_16x16x32_bf16(
            ah[mi], bl[ni], acc[mi][ni], 0, 0, 0);
      }
  }

#pragma unroll
  for (int ni = 0; ni < 2; ++ni) {
    const int col = col0 + wc + ni * 16 + lr;
    const float bv = bias[col];
#pragma unroll
    for (int mi = 0; mi < 4; ++mi) {
      const int rowb = row0 + wr + mi * 16 + (lane >> 4) * 4;
#pragma unroll
      for (int j = 0; j < 4; ++j) {
        float val = acc[mi][ni][j] + bv;
        if (RELU) val = fmaxf(val, 0.f);
        const size_t idx = (size_t)(rowb + j) * N + col;
        if (OUTBF16) {
          unsigned short hb = f32_to_bf16(val);
          Chi[idx] = hb;
          Clo[idx] = f32_to_bf16(val - bf16_to_f32(hb));
        } else {
          C[idx] = val;
        }
      }
    }
  }
}

// ---------------------------- MFMA flash attention (R8-validated) -----------
#define QB 64
#define KB 64

__global__ __launch_bounds__(256) void attn_mfma_kernel(
    const float* __restrict__ q, const float* __restrict__ k,
    const float* __restrict__ v, unsigned short* __restrict__ ohi,
    unsigned short* __restrict__ olo) {
  __shared__ unsigned short Kh[64 * 64], Kl[64 * 64];
  __shared__ unsigned short Vh[64 * 64], Vl[64 * 64];   // transposed [d][kk]
  __shared__ unsigned short Ph[4][16 * 64], Pl[4][16 * 64];

  const int tid = threadIdx.x;
  const int w = tid >> 6;
  const int l = tid & 63;
  const int lr = l & 15;
  const int lg = l >> 4;
  const int qb = blockIdx.x;
  const int bh = blockIdx.y;
  const int b = bh >> 4;
  const int h = bh & 15;
  const size_t base = (size_t)b * SEQ * D_MODEL + (size_t)h * D_K;

  shortx8 Qh[2], Ql[2];
  {
    const float* qrow = q + base + (size_t)(qb * QB + w * 16 + lr) * D_MODEL;
#pragma unroll
    for (int s = 0; s < 2; ++s) {
      float f[8];
      *(float4*)&f[0] = *(const float4*)&qrow[s * 32 + lg * 8];
      *(float4*)&f[4] = *(const float4*)&qrow[s * 32 + lg * 8 + 4];
#pragma unroll
      for (int j = 0; j < 8; ++j) f[j] *= 0.125f;
      split8(f, Qh[s], Ql[s]);
    }
  }

  floatx4 acc_o[4];
#pragma unroll
  for (int i = 0; i < 4; ++i) acc_o[i] = (floatx4)0.f;
  float m_run[4] = {-1e30f, -1e30f, -1e30f, -1e30f};
  float l_run[4] = {0.f, 0.f, 0.f, 0.f};

  for (int kt = 0; kt < SEQ / KB; ++kt) {
    __syncthreads();
#pragma unroll
    for (int it = 0; it < 2; ++it) {
      const int idx = tid + it * 256;
      const int kk = idx >> 3, dblk = idx & 7;
      const float* kr = k + base + (size_t)(kt * KB + kk) * D_MODEL + dblk * 8;
      float f[8];
      *(float4*)&f[0] = *(const float4*)kr;
      *(float4*)&f[4] = *(const float4*)(kr + 4);
      shortx8 hi, lo;
      split8(f, hi, lo);
      const int a = kk * 64 + ((dblk ^ (kk & 7)) * 8);
      *(shortx8*)&Kh[a] = hi;
      *(shortx8*)&Kl[a] = lo;
    }
#pragma unroll
    for (int it = 0; it < 2; ++it) {
      const int g = w + it * 4;
      const int d = l;
      float f[8];
#pragma unroll
      for (int j = 0; j < 8; ++j)
        f[j] = v[base + (size_t)(kt * KB + g * 8 + j) * D_MODEL + d];
      shortx8 hi, lo;
      split8(f, hi, lo);
      const int a = d * 64 + ((g ^ (d & 7)) * 8);
      *(shortx8*)&Vh[a] = hi;
      *(shortx8*)&Vl[a] = lo;
    }
    __syncthreads();

    floatx4 sfr[4];
#pragma unroll
    for (int f = 0; f < 4; ++f) {
      floatx4 acc = (floatx4)0.f;
      const int kk = f * 16 + lr;
#pragma unroll
      for (int s = 0; s < 2; ++s) {
        const int a = kk * 64 + (((s * 4 + lg) ^ (kk & 7)) * 8);
        shortx8 kbh = *(const shortx8*)&Kh[a];
        shortx8 kbl = *(const shortx8*)&Kl[a];
        acc = __builtin_amdgcn_mfma_f32_16x16x32_bf16(Qh[s], kbh, acc, 0, 0, 0);
        acc = __builtin_amdgcn_mfma_f32_16x16x32_bf16(Ql[s], kbh, acc, 0, 0, 0);
        acc = __builtin_amdgcn_mfma_f32_16x16x32_bf16(Qh[s], kbl, acc, 0, 0, 0);
      }
      sfr[f] = acc;
    }

    float corr[4];
#pragma unroll
    for (int j = 0; j < 4; ++j) {
      float tm = fmaxf(fmaxf(sfr[0][j], sfr[1][j]), fmaxf(sfr[2][j], sfr[3][j]));
      tm = fmaxf(tm, __shfl_xor(tm, 1));
      tm = fmaxf(tm, __shfl_xor(tm, 2));
      tm = fmaxf(tm, __shfl_xor(tm, 4));
      tm = fmaxf(tm, __shfl_xor(tm, 8));
      const float mn = fmaxf(m_run[j], tm);
      corr[j] = __expf(m_run[j] - mn);
      m_run[j] = mn;
      float ps = 0.f;
#pragma unroll
      for (int f = 0; f < 4; ++f) {
        float p = __expf(sfr[f][j] - mn);
        sfr[f][j] = p;
        ps += p;
      }
      ps += __shfl_xor(ps, 1);
      ps += __shfl_xor(ps, 2);
      ps += __shfl_xor(ps, 4);
      ps += __shfl_xor(ps, 8);
      l_run[j] = l_run[j] * corr[j] + ps;
#pragma unroll
      for (int nf = 0; nf < 4; ++nf) acc_o[nf][j] *= corr[j];
    }

    unsigned short* phw = &Ph[w][0];
    unsigned short* plw = &Pl[w][0];
#pragma unroll
    for (int f = 0; f < 4; ++f) {
      const int kk = f * 16 + lr;
      const int blk = kk >> 3;
      const int within = kk & 7;
#pragma unroll
      for (int j = 0; j < 4; ++j) {
        const int qr = lg * 4 + j;
        const float p = sfr[f][j];
        const unsigned short hb = f32_to_bf16(p);
        const int a = qr * 64 + ((blk ^ (qr & 7)) * 8) + within;
        phw[a] = hb;
        plw[a] = f32_to_bf16(p - bf16_to_f32(hb));
      }
    }

#pragma unroll
    for (int s2 = 0; s2 < 2; ++s2) {
      const int blk = (s2 * 4 + lg) ^ (lr & 7);
      shortx8 pah = *(const shortx8*)&Ph[w][lr * 64 + blk * 8];
      shortx8 pal = *(const shortx8*)&Pl[w][lr * 64 + blk * 8];
#pragma unroll
      for (int nf = 0; nf < 4; ++nf) {
        const int d = nf * 16 + lr;
        const int a = d * 64 + blk * 8;   // (d&7)==(lr&7) -> same swizzle
        shortx8 vbh = *(const shortx8*)&Vh[a];
        shortx8 vbl = *(const shortx8*)&Vl[a];
        acc_o[nf] = __builtin_amdgcn_mfma_f32_16x16x32_bf16(pah, vbh, acc_o[nf], 0, 0, 0);
        acc_o[nf] = __builtin_amdgcn_mfma_f32_16x16x32_bf16(pal, vbh, acc_o[nf], 0, 0, 0);
        acc_o[nf] = __builtin_amdgcn_mfma_f32_16x16x32_bf16(pah, vbl, acc_o[nf], 0, 0, 0);
      }
    }
  }

  float inv[4];
#pragma unroll
  for (int j = 0; j < 4; ++j) inv[j] = 1.f / l_run[j];
#pragma unroll
  for (int nf = 0; nf < 4; ++nf) {
    const int d = nf * 16 + lr;
#pragma unroll
    for (int j = 0; j < 4; ++j) {
      const int qr = lg * 4 + j;
      const float val = acc_o[nf][j] * inv[j];
      const size_t idx = base + (size_t)(qb * QB + w * 16 + qr) * D_MODEL + d;
      const unsigned short hb = f32_to_bf16(val);
      ohi[idx] = hb;
      olo[idx] = f32_to_bf16(val - bf16_to_f32(hb));
    }
  }
}

// ---------------------------- Add + LayerNorm (+ fused hi/lo split) ---------
__global__ __launch_bounds__(256) void add_ln_kernel(
    float* __restrict__ x, const float* __restrict__ t,
    const float* __restrict__ gamma, const float* __restrict__ beta,
    unsigned short* __restrict__ xh, unsigned short* __restrict__ xl) {
  const int row = blockIdx.x;
  const int tid = threadIdx.x;
  float* xrow = x + (size_t)row * D_MODEL;
  const float* trow = t + (size_t)row * D_MODEL;

  float4 xv = ((const float4*)xrow)[tid];
  float4 tv = ((const float4*)trow)[tid];
  float4 s;
  s.x = xv.x + tv.x; s.y = xv.y + tv.y;
  s.z = xv.z + tv.z; s.w = xv.w + tv.w;

  float sum = s.x + s.y + s.z + s.w;
  float sq = s.x * s.x + s.y * s.y + s.z * s.z + s.w * s.w;
#pragma unroll
  for (int off = 32; off > 0; off >>= 1) {
    sum += __shfl_down(sum, off);
    sq += __shfl_down(sq, off);
  }
  __shared__ float red[10];
  const int wave = tid >> 6;
  if ((tid & 63) == 0) { red[wave] = sum; red[wave + 4] = sq; }
  __syncthreads();
  if (tid == 0) {
    float S = red[0] + red[1] + red[2] + red[3];
    float Q = red[4] + red[5] + red[6] + red[7];
    float mu = S * (1.f / D_MODEL);
    float var = Q * (1.f / D_MODEL) - mu * mu;
    red[8] = mu;
    red[9] = rsqrtf(var + 1e-5f);
  }
  __syncthreads();
  const float mu = red[8], rstd = red[9];

  float4 gv = ((const float4*)gamma)[tid];
  float4 bv = ((const float4*)beta)[tid];
  float f[4];
  f[0] = (s.x - mu) * rstd * gv.x + bv.x;
  f[1] = (s.y - mu) * rstd * gv.y + bv.y;
  f[2] = (s.z - mu) * rstd * gv.z + bv.z;
  f[3] = (s.w - mu) * rstd * gv.w + bv.w;
  ((float4*)xrow)[tid] = make_float4(f[0], f[1], f[2], f[3]);

  ushortx4 h4, l4;
#pragma unroll
  for (int j = 0; j < 4; ++j) {
    unsigned short hb = f32_to_bf16(f[j]);
    h4[j] = hb;
    l4[j] = f32_to_bf16(f[j] - bf16_to_f32(hb));
  }
  const size_t o4 = (size_t)row * (D_MODEL / 4) + tid;
  ((ushortx4*)xh)[o4] = h4;
  ((ushortx4*)xl)[o4] = l4;
}

// ---------------------------- Launch ---------------------------------------
extern "C" void kernel_launch(void* const* d_in, const int* in_sizes, int n_in,
                              void* d_out, int out_size, void* d_ws,
                              size_t ws_size, hipStream_t stream) {
  const float* x  = (const float*)d_in[0];
  const float* Wq = (const float*)d_in[1];
  const float* bq = (const float*)d_in[2];
  const float* Wk = (const float*)d_in[3];
  const float* bk = (const float*)d_in[4];
  const float* Wv = (const float*)d_in[5];
  const float* bv = (const float*)d_in[6];
  const float* Wo = (const float*)d_in[7];
  const float* bo = (const float*)d_in[8];
  const float* W1 = (const float*)d_in[9];
  const float* b1 = (const float*)d_in[10];
  const float* W2 = (const float*)d_in[11];
  const float* b2 = (const float*)d_in[12];
  const float* g1 = (const float*)d_in[13];
  const float* be1 = (const float*)d_in[14];
  const float* g2 = (const float*)d_in[15];
  const float* be2 = (const float*)d_in[16];

  float* xb = (float*)d_out;               // residual stream (in place)
  char* ws = (char*)d_ws;
  const size_t MB = 1024ull * 1024ull;
  const size_t NTOK = (size_t)ROWS * D_MODEL;

  // activations
  float* qf = (float*)(ws + 0 * MB);       // 16 MB
  float* kf = (float*)(ws + 16 * MB);      // 16 MB
  float* vf = (float*)(ws + 32 * MB);      // 16 MB
  float* t0 = (float*)(ws + 64 * MB);      // 16 MB
  unsigned short* xh = (unsigned short*)(ws + 80 * MB);   // 8 MB
  unsigned short* xl = (unsigned short*)(ws + 88 * MB);   // 8 MB
  unsigned short* oh = (unsigned short*)(ws + 96 * MB);   // 8 MB
  unsigned short* ol = (unsigned short*)(ws + 104 * MB);  // 8 MB
  // FF hidden hi/lo overlaps q/k/v (dead after attention)
  unsigned short* hh = (unsigned short*)(ws + 0 * MB);    // 32 MB
  unsigned short* hl = (unsigned short*)(ws + 32 * MB);   // 32 MB
  // transposed weights (per layer)
  unsigned short* wqh = (unsigned short*)(ws + 112 * MB);
  unsigned short* wql = (unsigned short*)(ws + 114 * MB);
  unsigned short* wkh = (unsigned short*)(ws + 116 * MB);
  unsigned short* wkl = (unsigned short*)(ws + 118 * MB);
  unsigned short* wvh = (unsigned short*)(ws + 120 * MB);
  unsigned short* wvl = (unsigned short*)(ws + 122 * MB);
  unsigned short* woh = (unsigned short*)(ws + 124 * MB);
  unsigned short* wol = (unsigned short*)(ws + 126 * MB);
  unsigned short* w1h = (unsigned short*)(ws + 128 * MB);
  unsigned short* w1l = (unsigned short*)(ws + 136 * MB);
  unsigned short* w2h = (unsigned short*)(ws + 144 * MB);
  unsigned short* w2l = (unsigned short*)(ws + 152 * MB);  // end 160 MB

  hipMemcpyAsync(xb, x, NTOK * sizeof(float), hipMemcpyDeviceToDevice, stream);

  const dim3 blk(256);
  const dim3 g_dd(D_MODEL / GBN, ROWS / GBM);  // 16x32 = 512 blocks
  const dim3 g_df(D_FF / GBN, ROWS / GBM);     // 64x32 = 2048 blocks
  const dim3 attn_grid(SEQ / QB, BATCH * N_HEAD);
  const dim3 ln_grid(ROWS);
  const int n4tok = (int)(NTOK / 4);

  // initial x -> hi/lo (layers 1+ get xh/xl from add_ln2)
  split_kernel<<<dim3((n4tok + 255) / 256), blk, 0, stream>>>(xb, xh, xl, n4tok);

  for (int l = 0; l < LAYERS; ++l) {
    const float* Wq_l = Wq + (size_t)l * D_MODEL * D_MODEL;
    const float* Wk_l = Wk + (size_t)l * D_MODEL * D_MODEL;
    const float* Wv_l = Wv + (size_t)l * D_MODEL * D_MODEL;
    const float* Wo_l = Wo + (size_t)l * D_MODEL * D_MODEL;
    const float* W1_l = W1 + (size_t)l * D_MODEL * D_FF;
    const float* W2_l = W2 + (size_t)l * D_FF * D_MODEL;
    const float* bq_l = bq + (size_t)l * D_MODEL;
    const float* bk_l = bk + (size_t)l * D_MODEL;
    const float* bv_l = bv + (size_t)l * D_MODEL;
    const float* bo_l = bo + (size_t)l * D_MODEL;
    const float* b1_l = b1 + (size_t)l * D_FF;
    const float* b2_l = b2 + (size_t)l * D_MODEL;
    const float* g1_l = g1 + (size_t)l * D_MODEL;
    const float* be1_l = be1 + (size_t)l * D_MODEL;
    const float* g2_l = g2 + (size_t)l * D_MODEL;
    const float* be2_l = be2 + (size_t)l * D_MODEL;

    wtrans_qkvo_kernel<<<dim3(32, 32, 4), blk, 0, stream>>>(
        Wq_l, Wk_l, Wv_l, Wo_l, wqh, wql, wkh, wkl, wvh, wvl, woh, wol);
    wtrans_kernel<<<dim3(32, 128), blk, 0, stream>>>(W1_l, w1h, w1l, D_MODEL, D_FF);
    wtrans_kernel<<<dim3(128, 32), blk, 0, stream>>>(W2_l, w2h, w2l, D_FF, D_MODEL);

    gemm_mfma_kernel<0, 0><<<g_dd, blk, 0, stream>>>(
        xh, xl, wqh, wql, bq_l, qf, nullptr, nullptr, ROWS, D_MODEL, D_MODEL);
    gemm_mfma_kernel<0, 0><<<g_dd, blk, 0, stream>>>(
        xh, xl, wkh, wkl, bk_l, kf, nullptr, nullptr, ROWS, D_MODEL, D_MODEL);
    gemm_mfma_kernel<0, 0><<<g_dd, blk, 0, stream>>>(
        xh, xl, wvh, wvl, bv_l, vf, nullptr, nullptr, ROWS, D_MODEL, D_MODEL);

    attn_mfma_kernel<<<attn_grid, blk, 0, stream>>>(qf, kf, vf, oh, ol);

    gemm_mfma_kernel<0, 0><<<g_dd, blk, 0, stream>>>(
        oh, ol, woh, wol, bo_l, t0, nullptr, nullptr, ROWS, D_MODEL, D_MODEL);
    add_ln_kernel<<<ln_grid, blk, 0, stream>>>(xb, t0, g1_l, be1_l, xh, xl);

    gemm_mfma_kernel<1, 1><<<g_df, blk, 0, stream>>>(
        xh, xl, w1h, w1l, b1_l, nullptr, hh, hl, ROWS, D_FF, D_MODEL);
    gemm_mfma_kernel<0, 0><<<g_dd, blk, 0, stream>>>(
        hh, hl, w2h, w2l, b2_l, t0, nullptr, nullptr, ROWS, D_MODEL, D_FF);
    add_ln_kernel<<<ln_grid, blk, 0, stream>>>(xb, t0, g2_l, be2_l, xh, xl);
  }
}